// Round 1
// baseline (154.931 us; speedup 1.0000x reference)
//
#include <hip/hip_runtime.h>
#include <hip/hip_bf16.h>

// PureCascadedBitFFN: distance (512,4096) f32 -> bits (512,4096,16) f32.
// Reference cascade (MSB->LSB, sigmoid(S*(r - T + 0.5)) > 0.5) is bit-exact
// equivalent to N = ceil(d - 0.5) and emitting N's bits LSB-first:
//  - sigmoid(x) > 0.5  <=>  x > 0 (strict; min |nonzero arg| = 20*2^-24 ->
//    sigmoid rounds ~5 ulps above 0.5 in f32, so f32/f64 refs agree)
//  - every cascade subtraction is exact (Sterbenz: r in (T-0.5, 2T-0.5) when
//    bit=1), and the sign-ambiguous zone of t is always inside the exact
//    region, so fp cascade == exact-real cascade == bits of ceil(d - 0.5)
//  - d - 0.5f is exact for all f32 d in [0, 65536)
// Memory-bound: 8 MiB read + 128 MiB write -> ~24 us floor at ~6 TB/s.

#define NUM_BITS 16

__global__ __launch_bounds__(256) void cascaded_bits_kernel(
    const float* __restrict__ din, float* __restrict__ dout, int n) {
    int i = blockIdx.x * blockDim.x + threadIdx.x;
    if (i >= n) return;

    float d = din[i];
    // N = ceil(d - 0.5): exact match of the reference fp cascade (see header)
    unsigned N = (unsigned)(int)ceilf(d - 0.5f);

    float b[NUM_BITS];
#pragma unroll
    for (int j = 0; j < NUM_BITS; ++j) {
        b[j] = (float)((N >> j) & 1u);  // LSB at index 0, matching stack order
    }

    // 64 B contiguous per thread; 4x float4 stores. A wave's 4 store
    // instructions cover a contiguous 4 KB span; L2 merges partial lines.
    float4* out4 = (float4*)(dout + (size_t)i * NUM_BITS);
    out4[0] = make_float4(b[0],  b[1],  b[2],  b[3]);
    out4[1] = make_float4(b[4],  b[5],  b[6],  b[7]);
    out4[2] = make_float4(b[8],  b[9],  b[10], b[11]);
    out4[3] = make_float4(b[12], b[13], b[14], b[15]);
}

extern "C" void kernel_launch(void* const* d_in, const int* in_sizes, int n_in,
                              void* d_out, int out_size, void* d_ws, size_t ws_size,
                              hipStream_t stream) {
    const float* distance = (const float*)d_in[0];
    float* out = (float*)d_out;
    int n = in_sizes[0];  // 512*4096 = 2,097,152 elements

    const int block = 256;
    const int grid = (n + block - 1) / block;  // 8192 blocks
    cascaded_bits_kernel<<<grid, block, 0, stream>>>(distance, out, n);
}

// Round 2
// 142.509 us; speedup vs baseline: 1.0872x; 1.0872x over previous
//
#include <hip/hip_runtime.h>
#include <hip/hip_bf16.h>

// PureCascadedBitFFN: distance (512,4096) f32 -> bits (512,4096,16) f32.
// Reference cascade (MSB->LSB, sigmoid(S*(r - T + 0.5)) > 0.5) is bit-exact
// equivalent to N = ceil(d - 0.5), bits emitted LSB-first (proof in R0:
// sigmoid>0.5 <=> arg>0; all cascade subtractions Sterbenz-exact; d-0.5f
// exact for d in [0,65536)). Verified absmax 0.0 in R0.
//
// R1 fix: R0 gave each thread a 64 B output span -> per-instruction lane
// stride of 64 B -> 4x store-transaction amplification -> 0.92 TB/s.
// Now one thread per output float4: lane-contiguous 16 B/lane stores
// (1 KiB per wave store instruction), the same pattern the harness's
// fillBuffer sustains at 6.4 TB/s. Reads are 4x redundant per element but
// broadcast within a cache line; read stream (8 MiB) is noise vs 128 MiB
// write stream.

#define NUM_BITS 16

__global__ __launch_bounds__(256) void cascaded_bits_kernel(
    const float* __restrict__ din, float* __restrict__ dout, int n4) {
    int t = blockIdx.x * blockDim.x + threadIdx.x;
    if (t >= n4) return;

    int e = t >> 2;        // input element index
    int q = (t & 3) << 2;  // starting bit of this thread's 4-bit nibble

    float d = din[e];
    // N = ceil(d - 0.5): bit-exact match of the reference fp cascade
    unsigned N = (unsigned)(int)ceilf(d - 0.5f);

    float4 v = make_float4((float)((N >> (q + 0)) & 1u),
                           (float)((N >> (q + 1)) & 1u),
                           (float)((N >> (q + 2)) & 1u),
                           (float)((N >> (q + 3)) & 1u));

    ((float4*)dout)[t] = v;  // lane-contiguous: wave writes 1 KiB/instr
}

extern "C" void kernel_launch(void* const* d_in, const int* in_sizes, int n_in,
                              void* d_out, int out_size, void* d_ws, size_t ws_size,
                              hipStream_t stream) {
    const float* distance = (const float*)d_in[0];
    float* out = (float*)d_out;
    int n = in_sizes[0];      // 512*4096 = 2,097,152 elements
    int n4 = n * 4;           // one thread per output float4 (8,388,608)

    const int block = 256;
    const int grid = (n4 + block - 1) / block;  // 32768 blocks
    cascaded_bits_kernel<<<grid, block, 0, stream>>>(distance, out, n4);
}

// Round 3
// 140.220 us; speedup vs baseline: 1.1049x; 1.0163x over previous
//
#include <hip/hip_runtime.h>
#include <hip/hip_bf16.h>

// PureCascadedBitFFN: distance (512,4096) f32 -> bits (512,4096,16) f32.
// Reference cascade == bits of N = ceil(d - 0.5), LSB-first (proof R0:
// sigmoid>0.5 <=> arg>0; cascade subtractions Sterbenz-exact; d-0.5f exact
// on [0,65536)). absmax 0.0 verified in R0/R1.
//
// R1 -> R2: R1 was one store per wave then endpgm (32768 tiny workgroups):
// no sustained issue, ~2.4 TB/s effective. R2 is a persistent grid-stride
// kernel (2048 blocks = 8/CU, full 32-wave occupancy at low VGPR), 16
// float4 outputs per thread, unrolled x4 for 4 independent store chains in
// flight per wave -- mirroring the structure of the runtime's fill kernel
// that sustains 6.5 TB/s on this device.
// Store mapping unchanged from R1: thread <-> output float4, lane-contiguous
// 16 B/lane (1 KiB per wave store instruction). Input reads are 4x lane-
// redundant but only 64 B (one line) per wave per iteration.

#define NUM_BITS 16
#define UNROLL 4

__device__ __forceinline__ float4 nibble_of(const float* __restrict__ din, int t) {
    int e = t >> 2;        // input element
    int q = (t & 3) << 2;  // starting bit of this thread's nibble
    float d = din[e];
    unsigned N = (unsigned)(int)ceilf(d - 0.5f);  // == reference cascade value
    return make_float4((float)((N >> (q + 0)) & 1u),
                       (float)((N >> (q + 1)) & 1u),
                       (float)((N >> (q + 2)) & 1u),
                       (float)((N >> (q + 3)) & 1u));
}

__global__ __launch_bounds__(256) void cascaded_bits_kernel(
    const float* __restrict__ din, float4* __restrict__ dout, int n4) {
    const int stride = gridDim.x * blockDim.x;          // 524,288 threads
    int t0 = blockIdx.x * blockDim.x + threadIdx.x;

    // Main body: UNROLL independent iterations in flight per wave.
    int t = t0;
    for (; t + (UNROLL - 1) * stride < n4; t += UNROLL * stride) {
#pragma unroll
        for (int u = 0; u < UNROLL; ++u) {
            dout[t + u * stride] = nibble_of(din, t + u * stride);
        }
    }
    // Tail (empty for n4 = 8,388,608 with 2048x256 grid, kept for safety).
    for (; t < n4; t += stride) {
        dout[t] = nibble_of(din, t);
    }
}

extern "C" void kernel_launch(void* const* d_in, const int* in_sizes, int n_in,
                              void* d_out, int out_size, void* d_ws, size_t ws_size,
                              hipStream_t stream) {
    const float* distance = (const float*)d_in[0];
    float4* out = (float4*)d_out;
    int n = in_sizes[0];      // 512*4096 = 2,097,152 elements
    int n4 = n * 4;           // 8,388,608 output float4s

    const int block = 256;
    const int grid = 2048;    // 8 blocks/CU on 256 CUs; 16 float4s/thread
    cascaded_bits_kernel<<<grid, block, 0, stream>>>(distance, out, n4);
}